// Round 2
// baseline (2157.621 us; speedup 1.0000x reference)
//
#include <hip/hip_runtime.h>
#include <hip/hip_bf16.h>

// LSAPPNP: h = relu(x@W1+b1); h2 = h@W2+b2; agg[r] += val*h2[c] over edges;
// out = log_softmax(0.1*h2 + agg, axis=1)
// N=100000, F_IN=500, HID=256, C=40, E~2.3M

#define N_NODES 100000
#define F_IN    500
#define HID     256
#define C_OUT   40
#define ALPHA0  0.1f

typedef short short8 __attribute__((ext_vector_type(8)));
typedef float f32x4  __attribute__((ext_vector_type(4)));

__device__ __forceinline__ short f2bf(float f) {
  union { float f; unsigned u; } x; x.f = f;
  unsigned r = x.u + 0x7fffu + ((x.u >> 16) & 1u);  // RNE
  return (short)(r >> 16);
}

// ---- K0: pack W1 -> W1S [16 kchunks][256 n][32 k] bf16 (zero-pad k>=500)
//          pack W2 -> W2T [48 n][256 k] bf16 (zero-pad n>=40)
__global__ __launch_bounds__(256) void k_pack_weights(
    const float* __restrict__ W1, const float* __restrict__ W2,
    short* __restrict__ W1S, short* __restrict__ W2T)
{
  int i = blockIdx.x * 256 + threadIdx.x;
  if (i < 16*256*32) {
    int kc  = i >> 13;
    int idx = i & 8191;
    int n   = idx >> 5;
    int kk  = idx & 31;
    int k   = kc*32 + kk;
    float v = (k < F_IN) ? W1[k*HID + n] : 0.f;
    W1S[i] = f2bf(v);
  } else {
    int j = i - 16*256*32;
    if (j < 48*256) {
      int n = j >> 8;
      int k = j & 255;
      float v = (n < C_OUT) ? W2[k*C_OUT + n] : 0.f;
      W2T[j] = f2bf(v);
    }
  }
}

// ---- K1: fused MLP. Block = 256 thr (4 waves), tile = 64 rows x 256 (full HID).
// GEMM1 via mfma_f32_16x16x32_bf16, relu+b1 -> Hl (bf16 LDS),
// GEMM2 (K=256, 48 padded cols) -> h2, accb = alpha*h2.
__global__ __launch_bounds__(256) void k_fused_mlp(
    const float* __restrict__ x, const float* __restrict__ b1v,
    const float* __restrict__ b2v,
    const short* __restrict__ W1S, const short* __restrict__ W2T,
    float* __restrict__ h2, float* __restrict__ accb)
{
  // LDS: [Al 4KB | Bl 16KB] union'd with [Hl 32KB], then W2l 24KB => 56KB total
  __shared__ __align__(16) char smem[57344];
  short (*Al)[32]   = (short(*)[32])smem;
  short (*Bl)[32]   = (short(*)[32])(smem + 4096);
  short (*Hl)[256]  = (short(*)[256])smem;            // overlaps Al+Bl (used after K loop)
  short (*W2l)[256] = (short(*)[256])(smem + 32768);

  const int tid  = threadIdx.x;
  const int wave = tid >> 6;
  const int lane = tid & 63;
  const int lr   = lane & 15;   // A-row / B-col / D-col within 16-tile
  const int quad = lane >> 4;   // k-group for A/B frags; row-group for D
  const int row0 = blockIdx.x * 64;

  // stage W2T (12288 shorts = 1536 short8) -> W2l, coalesced: 6 iters x 256 thr
  {
    const short8* src = (const short8*)W2T;
    short8* dst = (short8*)&W2l[0][0];
    #pragma unroll
    for (int it = 0; it < 6; ++it)
      dst[it*256 + tid] = src[it*256 + tid];
  }

  f32x4 acc[4][4] = {};  // [row-tile][col-tile], 16x16 each

  const int ar = tid >> 2;                       // A staging: row 0..63
  const int aq = tid & 3;                        // col group of 8
  const bool arow_ok = (row0 + ar) < N_NODES;
  const float* asrc = x + (long)(row0 + ar) * F_IN + aq*8;

  for (int kc = 0; kc < 16; ++kc) {
    // ---- stage A tile (64x32 f32 -> bf16), coalesced 128B per 4 lanes
    {
      short tmp[8];
      int kbase = kc*32 + aq*8;
      if (arow_ok) {
        #pragma unroll
        for (int j = 0; j < 8; ++j) {
          float v = (kbase + j < F_IN) ? asrc[kc*32 + j] : 0.f;
          tmp[j] = f2bf(v);
        }
      } else {
        #pragma unroll
        for (int j = 0; j < 8; ++j) tmp[j] = 0;
      }
      *(short8*)&Al[ar][aq*8] = *(short8*)tmp;
    }
    // ---- stage B tile: W1S chunk is contiguous 16KB -> perfectly coalesced
    {
      const short* src = W1S + kc*8192 + tid*32;
      short* dst = &Bl[0][0] + tid*32;
      #pragma unroll
      for (int j = 0; j < 4; ++j)
        *(short8*)(dst + j*8) = *(const short8*)(src + j*8);
    }
    __syncthreads();

    short8 af[4], bfr[4];
    #pragma unroll
    for (int t = 0; t < 4; ++t) af[t]  = *(const short8*)&Al[t*16 + lr][quad*8];
    #pragma unroll
    for (int t = 0; t < 4; ++t) bfr[t] = *(const short8*)&Bl[wave*64 + t*16 + lr][quad*8];

    #pragma unroll
    for (int rt = 0; rt < 4; ++rt)
      #pragma unroll
      for (int ct = 0; ct < 4; ++ct)
        acc[rt][ct] = __builtin_amdgcn_mfma_f32_16x16x32_bf16(af[rt], bfr[ct], acc[rt][ct], 0, 0, 0);

    __syncthreads();
  }

  // ---- epilogue 1: relu(acc + b1) -> Hl bf16. D layout: col=lane&15, row=quad*4+reg
  #pragma unroll
  for (int ct = 0; ct < 4; ++ct) {
    int col = wave*64 + ct*16 + lr;
    float bias = b1v[col];
    #pragma unroll
    for (int rt = 0; rt < 4; ++rt) {
      #pragma unroll
      for (int r = 0; r < 4; ++r) {
        int row = rt*16 + quad*4 + r;
        float v = fmaxf(acc[rt][ct][r] + bias, 0.f);
        Hl[row][col] = f2bf(v);
      }
    }
  }
  __syncthreads();

  // ---- GEMM2: each wave does rows wave*16..+15, 48 cols (3 n-tiles), K=256
  f32x4 acc2[3] = {};
  #pragma unroll
  for (int kc2 = 0; kc2 < 8; ++kc2) {
    short8 a2 = *(const short8*)&Hl[wave*16 + lr][kc2*32 + quad*8];
    #pragma unroll
    for (int nt = 0; nt < 3; ++nt) {
      short8 bq = *(const short8*)&W2l[nt*16 + lr][kc2*32 + quad*8];
      acc2[nt] = __builtin_amdgcn_mfma_f32_16x16x32_bf16(a2, bq, acc2[nt], 0, 0, 0);
    }
  }

  // ---- epilogue 2: h2 = acc2 + b2; accb = alpha*h2
  #pragma unroll
  for (int nt = 0; nt < 3; ++nt) {
    int col = nt*16 + lr;
    if (col < C_OUT) {
      float bias = b2v[col];
      #pragma unroll
      for (int r = 0; r < 4; ++r) {
        int row = row0 + wave*16 + quad*4 + r;
        if (row < N_NODES) {
          float v = acc2[nt][r] + bias;
          long o = (long)row * C_OUT + col;
          h2[o]   = v;
          accb[o] = ALPHA0 * v;
        }
      }
    }
  }
}

// ---- K2: scatter-add propagation. 8 threads/edge, 5 cols each.
__global__ __launch_bounds__(256) void k_scatter(
    const int* __restrict__ erow, const int* __restrict__ ecol,
    const float* __restrict__ eval,
    const float* __restrict__ h2, float* __restrict__ accb, int E)
{
  int i = blockIdx.x * 256 + threadIdx.x;
  int e = i >> 3;
  if (e >= E) return;
  int s = i & 7;
  int r = erow[e], c = ecol[e];
  float v = eval[e];
  const float* hp = h2   + (long)c * C_OUT + s*5;
  float*       ap = accb + (long)r * C_OUT + s*5;
  #pragma unroll
  for (int j = 0; j < 5; ++j)
    unsafeAtomicAdd(ap + j, v * hp[j]);
}

// ---- K3: row-wise log_softmax over 40 classes. One wave per row.
__global__ __launch_bounds__(256) void k_logsoftmax(
    const float* __restrict__ accb, float* __restrict__ out)
{
  int row  = blockIdx.x * 4 + (threadIdx.x >> 6);
  int lane = threadIdx.x & 63;
  if (row >= N_NODES) return;
  float v = (lane < C_OUT) ? accb[row * C_OUT + lane] : -INFINITY;
  float m = v;
  #pragma unroll
  for (int o = 32; o > 0; o >>= 1) m = fmaxf(m, __shfl_xor(m, o));
  float ev = (lane < C_OUT) ? __expf(v - m) : 0.f;
  float s = ev;
  #pragma unroll
  for (int o = 32; o > 0; o >>= 1) s += __shfl_xor(s, o);
  if (lane < C_OUT) out[row * C_OUT + lane] = v - m - __logf(s);
}

extern "C" void kernel_launch(void* const* d_in, const int* in_sizes, int n_in,
                              void* d_out, int out_size, void* d_ws, size_t ws_size,
                              hipStream_t stream) {
  const float* x    = (const float*)d_in[0];
  const float* W1   = (const float*)d_in[1];
  const float* b1   = (const float*)d_in[2];
  const float* W2   = (const float*)d_in[3];
  const float* b2   = (const float*)d_in[4];
  const int*   erow = (const int*)d_in[5];
  const int*   ecol = (const int*)d_in[6];
  const float* eval = (const float*)d_in[7];
  const int E = in_sizes[5];

  // workspace layout (32.3 MB): h2 f32 16MB | accb f32 16MB | W1S bf16 256KB | W2T bf16 24KB
  float* h2   = (float*)d_ws;
  float* accb = h2 + (size_t)N_NODES * C_OUT;
  short* W1S  = (short*)(accb + (size_t)N_NODES * C_OUT);
  short* W2T  = W1S + 16*256*32;
  float* out  = (float*)d_out;

  k_pack_weights<<<(16*256*32 + 48*256 + 255)/256, 256, 0, stream>>>(W1, W2, W1S, W2T);
  k_fused_mlp<<<(N_NODES + 63)/64, 256, 0, stream>>>(x, b1, b2, W1S, W2T, h2, accb);
  {
    long threads = (long)E * 8;
    int blocks = (int)((threads + 255) / 256);
    k_scatter<<<blocks, 256, 0, stream>>>(erow, ecol, eval, h2, accb, E);
  }
  k_logsoftmax<<<(N_NODES + 3)/4, 256, 0, stream>>>(accb, out);
}

// Round 3
// 809.606 us; speedup vs baseline: 2.6650x; 2.6650x over previous
//
#include <hip/hip_runtime.h>
#include <hip/hip_bf16.h>

// LSAPPNP: h = relu(x@W1+b1); h2 = h@W2+b2; agg[r] += val*h2[c] over edges;
// out = log_softmax(0.1*h2 + agg, axis=1)
// N=100000, F_IN=500, HID=256, C=40, E~2.3M
//
// Round 3: scatter-atomics (2.08 GB HBM write-through, 1778 us) replaced by
// counting-sort CSR build + gather-reduce SpMM with fused log_softmax.

#define N_NODES 100000
#define F_IN    500
#define HID     256
#define C_OUT   40
#define ALPHA0  0.1f
#define SCAN_CHUNK 1024           // elements per scan1 block
#define NB_SCAN ((N_NODES + SCAN_CHUNK - 1) / SCAN_CHUNK)   // 98

typedef short short8 __attribute__((ext_vector_type(8)));
typedef float f32x4  __attribute__((ext_vector_type(4)));

__device__ __forceinline__ short f2bf(float f) {
  union { float f; unsigned u; } x; x.f = f;
  unsigned r = x.u + 0x7fffu + ((x.u >> 16) & 1u);  // RNE
  return (short)(r >> 16);
}
__device__ __forceinline__ float bf2f(short s) {
  union { unsigned u; float f; } x; x.u = ((unsigned)(unsigned short)s) << 16;
  return x.f;
}

// ---- K0: pack W1 -> W1S [16 kchunks][256 n][32 k] bf16 (zero-pad k>=500)
//          pack W2 -> W2T [48 n][256 k] bf16 (zero-pad n>=40)
__global__ __launch_bounds__(256) void k_pack_weights(
    const float* __restrict__ W1, const float* __restrict__ W2,
    short* __restrict__ W1S, short* __restrict__ W2T)
{
  int i = blockIdx.x * 256 + threadIdx.x;
  if (i < 16*256*32) {
    int kc  = i >> 13;
    int idx = i & 8191;
    int n   = idx >> 5;
    int kk  = idx & 31;
    int k   = kc*32 + kk;
    float v = (k < F_IN) ? W1[k*HID + n] : 0.f;
    W1S[i] = f2bf(v);
  } else {
    int j = i - 16*256*32;
    if (j < 48*256) {
      int n = j >> 8;
      int k = j & 255;
      float v = (n < C_OUT) ? W2[k*C_OUT + n] : 0.f;
      W2T[j] = f2bf(v);
    }
  }
}

// ---- K1: fused MLP. Block = 256 thr (4 waves), tile = 64 rows x 256 (full HID).
__global__ __launch_bounds__(256) void k_fused_mlp(
    const float* __restrict__ x, const float* __restrict__ b1v,
    const float* __restrict__ b2v,
    const short* __restrict__ W1S, const short* __restrict__ W2T,
    float* __restrict__ h2, short* __restrict__ h2b)
{
  // LDS: [Al 4KB | Bl 16KB] union'd with [Hl 32KB], then W2l 24KB => 56KB total
  __shared__ __align__(16) char smem[57344];
  short (*Al)[32]   = (short(*)[32])smem;
  short (*Bl)[32]   = (short(*)[32])(smem + 4096);
  short (*Hl)[256]  = (short(*)[256])smem;            // overlaps Al+Bl (used after K loop)
  short (*W2l)[256] = (short(*)[256])(smem + 32768);

  const int tid  = threadIdx.x;
  const int wave = tid >> 6;
  const int lane = tid & 63;
  const int lr   = lane & 15;
  const int quad = lane >> 4;
  const int row0 = blockIdx.x * 64;

  // stage W2T (1536 short8) -> W2l
  {
    const short8* src = (const short8*)W2T;
    short8* dst = (short8*)&W2l[0][0];
    #pragma unroll
    for (int it = 0; it < 6; ++it)
      dst[it*256 + tid] = src[it*256 + tid];
  }

  f32x4 acc[4][4] = {};

  const int ar = tid >> 2;
  const int aq = tid & 3;
  const bool arow_ok = (row0 + ar) < N_NODES;
  const float* asrc = x + (long)(row0 + ar) * F_IN + aq*8;

  for (int kc = 0; kc < 16; ++kc) {
    {
      short tmp[8];
      int kbase = kc*32 + aq*8;
      if (arow_ok) {
        #pragma unroll
        for (int j = 0; j < 8; ++j) {
          float v = (kbase + j < F_IN) ? asrc[kc*32 + j] : 0.f;
          tmp[j] = f2bf(v);
        }
      } else {
        #pragma unroll
        for (int j = 0; j < 8; ++j) tmp[j] = 0;
      }
      *(short8*)&Al[ar][aq*8] = *(short8*)tmp;
    }
    {
      const short* src = W1S + kc*8192 + tid*32;
      short* dst = &Bl[0][0] + tid*32;
      #pragma unroll
      for (int j = 0; j < 4; ++j)
        *(short8*)(dst + j*8) = *(const short8*)(src + j*8);
    }
    __syncthreads();

    short8 af[4], bfr[4];
    #pragma unroll
    for (int t = 0; t < 4; ++t) af[t]  = *(const short8*)&Al[t*16 + lr][quad*8];
    #pragma unroll
    for (int t = 0; t < 4; ++t) bfr[t] = *(const short8*)&Bl[wave*64 + t*16 + lr][quad*8];

    #pragma unroll
    for (int rt = 0; rt < 4; ++rt)
      #pragma unroll
      for (int ct = 0; ct < 4; ++ct)
        acc[rt][ct] = __builtin_amdgcn_mfma_f32_16x16x32_bf16(af[rt], bfr[ct], acc[rt][ct], 0, 0, 0);

    __syncthreads();
  }

  // epilogue 1: relu(acc + b1) -> Hl bf16. D layout: col=lane&15, row=quad*4+reg
  #pragma unroll
  for (int ct = 0; ct < 4; ++ct) {
    int col = wave*64 + ct*16 + lr;
    float bias = b1v[col];
    #pragma unroll
    for (int rt = 0; rt < 4; ++rt) {
      #pragma unroll
      for (int r = 0; r < 4; ++r) {
        int row = rt*16 + quad*4 + r;
        float v = fmaxf(acc[rt][ct][r] + bias, 0.f);
        Hl[row][col] = f2bf(v);
      }
    }
  }
  __syncthreads();

  // GEMM2: each wave rows wave*16..+15, 48 padded cols, K=256
  f32x4 acc2[3] = {};
  #pragma unroll
  for (int kc2 = 0; kc2 < 8; ++kc2) {
    short8 a2 = *(const short8*)&Hl[wave*16 + lr][kc2*32 + quad*8];
    #pragma unroll
    for (int nt = 0; nt < 3; ++nt) {
      short8 bq = *(const short8*)&W2l[nt*16 + lr][kc2*32 + quad*8];
      acc2[nt] = __builtin_amdgcn_mfma_f32_16x16x32_bf16(a2, bq, acc2[nt], 0, 0, 0);
    }
  }

  // epilogue 2: h2 = acc2 + b2 (f32 + bf16 copies)
  #pragma unroll
  for (int nt = 0; nt < 3; ++nt) {
    int col = nt*16 + lr;
    if (col < C_OUT) {
      float bias = b2v[col];
      #pragma unroll
      for (int r = 0; r < 4; ++r) {
        int row = row0 + wave*16 + quad*4 + r;
        if (row < N_NODES) {
          float v = acc2[nt][r] + bias;
          long o = (long)row * C_OUT + col;
          h2[o]  = v;
          h2b[o] = f2bf(v);
        }
      }
    }
  }
}

// ---- K2a: zero degree counters
__global__ __launch_bounds__(256) void k_zero(int* __restrict__ p, int n) {
  int i = blockIdx.x * 256 + threadIdx.x;
  if (i < n) p[i] = 0;
}

// ---- K2b: histogram of destination rows
__global__ __launch_bounds__(256) void k_hist(
    const int* __restrict__ erow, int* __restrict__ deg, int E)
{
  int e = blockIdx.x * 256 + threadIdx.x;
  if (e < E) atomicAdd(&deg[erow[e]], 1);
}

// ---- K2c: scan phase 1 — per-block (1024 elems) exclusive scan + block sums
__global__ __launch_bounds__(256) void k_scan1(
    const int* __restrict__ deg, int* __restrict__ offs, int* __restrict__ bsums)
{
  __shared__ int sh[256];
  int tid = threadIdx.x;
  int base = blockIdx.x * SCAN_CHUNK + tid * 4;
  int d[4];
  #pragma unroll
  for (int k = 0; k < 4; ++k)
    d[k] = (base + k < N_NODES) ? deg[base + k] : 0;
  int s = d[0] + d[1] + d[2] + d[3];
  sh[tid] = s;
  __syncthreads();
  for (int o = 1; o < 256; o <<= 1) {
    int v = (tid >= o) ? sh[tid - o] : 0;
    __syncthreads();
    if (tid >= o) sh[tid] += v;
    __syncthreads();
  }
  int excl = sh[tid] - s;
  int run = excl;
  #pragma unroll
  for (int k = 0; k < 4; ++k) {
    if (base + k < N_NODES) offs[base + k] = run;
    run += d[k];
  }
  if (tid == 255) bsums[blockIdx.x] = sh[255];
}

// ---- K2d: scan phase 2 — exclusive scan of NB_SCAN block sums (single block)
__global__ __launch_bounds__(128) void k_scan2(int* __restrict__ bsums) {
  __shared__ int sh[128];
  int tid = threadIdx.x;
  int v = (tid < NB_SCAN) ? bsums[tid] : 0;
  sh[tid] = v;
  __syncthreads();
  for (int o = 1; o < 128; o <<= 1) {
    int u = (tid >= o) ? sh[tid - o] : 0;
    __syncthreads();
    if (tid >= o) sh[tid] += u;
    __syncthreads();
  }
  if (tid < NB_SCAN) bsums[tid] = sh[tid] - v;
}

// ---- K2e: scan phase 3 — add block offsets; init cursors; offs[N]=E
__global__ __launch_bounds__(256) void k_scan3(
    int* __restrict__ offs, const int* __restrict__ bsums,
    int* __restrict__ cursor, int E)
{
  int i = blockIdx.x * 256 + threadIdx.x;
  if (i < N_NODES) {
    int v = offs[i] + bsums[i >> 10];
    offs[i] = v;
    cursor[i] = v;
  }
  if (i == 0) offs[N_NODES] = E;
}

// ---- K2f: bucket edges into CSR order: sorted[pos] = {col, val}
__global__ __launch_bounds__(256) void k_bucket(
    const int* __restrict__ erow, const int* __restrict__ ecol,
    const float* __restrict__ eval, int* __restrict__ cursor,
    int2* __restrict__ sorted, int E)
{
  int e = blockIdx.x * 256 + threadIdx.x;
  if (e >= E) return;
  int r = erow[e];
  int pos = atomicAdd(&cursor[r], 1);
  int2 cv; cv.x = ecol[e]; cv.y = __float_as_int(eval[e]);
  sorted[pos] = cv;
}

// ---- K3: gather-reduce SpMM + fused log_softmax. One wave per row.
__global__ __launch_bounds__(256) void k_spmm_lsm(
    const int* __restrict__ offs, const int2* __restrict__ sorted,
    const float* __restrict__ h2, const short* __restrict__ h2b,
    float* __restrict__ out)
{
  int row  = blockIdx.x * 4 + (threadIdx.x >> 6);
  int lane = threadIdx.x & 63;
  if (row >= N_NODES) return;

  float acc = 0.f;
  if (lane < C_OUT) acc = ALPHA0 * h2[row * C_OUT + lane];

  int e   = offs[row];
  int end = offs[row + 1];
  // 2x unrolled gather-accumulate (indep loads for latency overlap)
  for (; e + 1 < end; e += 2) {
    int2 cv0 = sorted[e];
    int2 cv1 = sorted[e + 1];
    float v0 = __int_as_float(cv0.y);
    float v1 = __int_as_float(cv1.y);
    if (lane < C_OUT) {
      float g0 = bf2f(h2b[cv0.x * C_OUT + lane]);
      float g1 = bf2f(h2b[cv1.x * C_OUT + lane]);
      acc += v0 * g0;
      acc += v1 * g1;
    }
  }
  if (e < end) {
    int2 cv = sorted[e];
    float v = __int_as_float(cv.y);
    if (lane < C_OUT) acc += v * bf2f(h2b[cv.x * C_OUT + lane]);
  }

  // fused log_softmax over the 40 active lanes
  float m = (lane < C_OUT) ? acc : -INFINITY;
  #pragma unroll
  for (int o = 32; o > 0; o >>= 1) m = fmaxf(m, __shfl_xor(m, o));
  float ev = (lane < C_OUT) ? __expf(acc - m) : 0.f;
  float s = ev;
  #pragma unroll
  for (int o = 32; o > 0; o >>= 1) s += __shfl_xor(s, o);
  if (lane < C_OUT) out[row * C_OUT + lane] = acc - m - __logf(s);
}

extern "C" void kernel_launch(void* const* d_in, const int* in_sizes, int n_in,
                              void* d_out, int out_size, void* d_ws, size_t ws_size,
                              hipStream_t stream) {
  const float* x    = (const float*)d_in[0];
  const float* W1   = (const float*)d_in[1];
  const float* b1   = (const float*)d_in[2];
  const float* W2   = (const float*)d_in[3];
  const float* b2   = (const float*)d_in[4];
  const int*   erow = (const int*)d_in[5];
  const int*   ecol = (const int*)d_in[6];
  const float* eval = (const float*)d_in[7];
  const int E = in_sizes[5];

  // ws layout: h2 f32 16MB | h2b bf16 8MB | W1S 256KB | W2T 24KB |
  //            offs (N+1) | cursor N | bsums | sorted E*8B   (~43.6 MB)
  char* p = (char*)d_ws;
  float* h2   = (float*)p;              p += (size_t)N_NODES * C_OUT * 4;
  short* h2b  = (short*)p;              p += (size_t)N_NODES * C_OUT * 2;
  short* W1S  = (short*)p;              p += 16*256*32 * 2;
  short* W2T  = (short*)p;              p += 48*256 * 2;
  int*   offs = (int*)p;                p += ((size_t)N_NODES + 4) * 4;
  int*   cursor = (int*)p;              p += (size_t)N_NODES * 4;
  int*   bsums  = (int*)p;              p += 128 * 4;
  int2*  sorted = (int2*)p;
  float* out  = (float*)d_out;

  k_pack_weights<<<(16*256*32 + 48*256 + 255)/256, 256, 0, stream>>>(W1, W2, W1S, W2T);
  k_fused_mlp<<<(N_NODES + 63)/64, 256, 0, stream>>>(x, b1, b2, W1S, W2T, h2, h2b);
  k_zero<<<(N_NODES + 255)/256, 256, 0, stream>>>(cursor, N_NODES);
  k_hist<<<(E + 255)/256, 256, 0, stream>>>(erow, cursor, E);
  k_scan1<<<NB_SCAN, 256, 0, stream>>>(cursor, offs, bsums);
  k_scan2<<<1, 128, 0, stream>>>(bsums);
  k_scan3<<<(N_NODES + 255)/256, 256, 0, stream>>>(offs, bsums, cursor, E);
  k_bucket<<<(E + 255)/256, 256, 0, stream>>>(erow, ecol, eval, cursor, sorted, E);
  k_spmm_lsm<<<(N_NODES + 3)/4, 256, 0, stream>>>(offs, sorted, h2, h2b, out);
}